// Round 1
// baseline (2344.865 us; speedup 1.0000x reference)
//
#include <hip/hip_runtime.h>
#include <hip/hip_bf16.h>
#include <math.h>

#define SEQ 64
#define IN_DIM 16384
#define H_DIM 1024
#define G4 4096   // 4*H
#define BATCH 40
#define NB_SCAN 256

// ---------------- ws layout (floats) ----------------
// [0 .. 256)            barrier (cnt at u32[0], gen at u32[32])
// [256 .. +1048576)     fT   : features transposed [16384][64]
// [.. +262144)          xw   : [64][4096]
// [.. +1024)            h_buf: [1024]
// [.. +65536)           hs_c : [64][1024]
// [.. +KS*262144)       part : [KS][64][4096]
#define OFF_FT   256
#define OFF_XW   (OFF_FT + (size_t)IN_DIM*SEQ)            // 1048832
#define OFF_H    (OFF_XW + (size_t)SEQ*G4)                // +262144
#define OFF_HS   (OFF_H + H_DIM)
#define OFF_PART (OFF_HS + (size_t)SEQ*H_DIM)

// ---------------- zero the barrier words ----------------
__global__ void zero_bar(unsigned* bar) {
    bar[threadIdx.x] = 0u;
}

// ---------------- transpose features [64][16384] -> fT [16384][64] ----------------
__global__ __launch_bounds__(256) void transpose_f(const float* __restrict__ f,
                                                   float* __restrict__ fT) {
    __shared__ float lds[64][65];
    const int kb = blockIdx.x;          // 256 blocks, 64-wide k tile
    const int tx = threadIdx.x & 63;    // k within tile
    const int ty = threadIdx.x >> 6;    // 0..3
#pragma unroll
    for (int i = 0; i < 16; ++i) {
        int t = ty * 16 + i;
        lds[tx][t] = f[(size_t)t * IN_DIM + kb * 64 + tx];
    }
    __syncthreads();
#pragma unroll
    for (int i = 0; i < 16; ++i) {
        int r = ty * 16 + i;            // k row within tile
        fT[(size_t)(kb * 64 + r) * 64 + tx] = lds[r][tx];
    }
}

// ---------------- GEMM partials: part[ks][t][j] = sum_{k in split} fT[k][t]*w_ih[j][k] ----------------
__global__ __launch_bounds__(256) void gemm_partial(const float* __restrict__ w_ih,
                                                    const float* __restrict__ fT,
                                                    float* __restrict__ part,
                                                    int kspan) {
    const int tid = threadIdx.x;
    const int j  = blockIdx.x * 256 + tid;   // 16 j-blocks
    const int t0 = blockIdx.y * 16;          // 4 t-blocks
    const int k0 = blockIdx.z * kspan;       // KS k-splits

    float acc[16];
#pragma unroll
    for (int i = 0; i < 16; ++i) acc[i] = 0.f;

    const float* wrow = w_ih + (size_t)j * IN_DIM;
    for (int kc = k0; kc < k0 + kspan; kc += 16) {
        const float4* wp = (const float4*)(wrow + kc);
        float warr[16];
        *(float4*)&warr[0]  = wp[0];
        *(float4*)&warr[4]  = wp[1];
        *(float4*)&warr[8]  = wp[2];
        *(float4*)&warr[12] = wp[3];
        const float* fbase = fT + (size_t)kc * 64 + t0;
#pragma unroll
        for (int kk = 0; kk < 16; ++kk) {
            const float wv = warr[kk];
            const float4* fp = (const float4*)(fbase + kk * 64);
            float4 f0 = fp[0], f1 = fp[1], f2 = fp[2], f3 = fp[3];
            acc[0]  += wv * f0.x; acc[1]  += wv * f0.y; acc[2]  += wv * f0.z; acc[3]  += wv * f0.w;
            acc[4]  += wv * f1.x; acc[5]  += wv * f1.y; acc[6]  += wv * f1.z; acc[7]  += wv * f1.w;
            acc[8]  += wv * f2.x; acc[9]  += wv * f2.y; acc[10] += wv * f2.z; acc[11] += wv * f2.w;
            acc[12] += wv * f3.x; acc[13] += wv * f3.y; acc[14] += wv * f3.z; acc[15] += wv * f3.w;
        }
    }
    float* pp = part + ((size_t)blockIdx.z * SEQ + t0) * G4 + j;
#pragma unroll
    for (int i = 0; i < 16; ++i) pp[(size_t)i * G4] = acc[i];
}

// ---------------- reduce partials + bias -> xw ----------------
__global__ __launch_bounds__(256) void reduce_xw(const float* __restrict__ part,
                                                 const float* __restrict__ b_ih,
                                                 const float* __restrict__ b_hh,
                                                 float* __restrict__ xw, int KS) {
    const int idx = blockIdx.x * 256 + threadIdx.x;  // t*4096 + j
    const int j = idx & (G4 - 1);
    float s = b_ih[j] + b_hh[j];
    for (int ks = 0; ks < KS; ++ks) s += part[(size_t)ks * (SEQ * G4) + idx];
    xw[idx] = s;
}

// ---------------- grid barrier ----------------
__device__ __forceinline__ void gridBarrier(unsigned* cnt, unsigned* gen, unsigned nb) {
    __threadfence();      // agent-scope release of our h stores
    __syncthreads();
    if (threadIdx.x == 0) {
        unsigned g = __hip_atomic_load(gen, __ATOMIC_RELAXED, __HIP_MEMORY_SCOPE_AGENT);
        unsigned prev = __hip_atomic_fetch_add(cnt, 1u, __ATOMIC_ACQ_REL, __HIP_MEMORY_SCOPE_AGENT);
        if (prev == nb - 1) {
            __hip_atomic_store(cnt, 0u, __ATOMIC_RELAXED, __HIP_MEMORY_SCOPE_AGENT);
            __hip_atomic_store(gen, g + 1u, __ATOMIC_RELEASE, __HIP_MEMORY_SCOPE_AGENT);
        } else {
            while (__hip_atomic_load(gen, __ATOMIC_RELAXED, __HIP_MEMORY_SCOPE_AGENT) == g) {
                __builtin_amdgcn_s_sleep(4);
            }
        }
    }
    __syncthreads();
    __builtin_amdgcn_fence(__ATOMIC_ACQUIRE, "agent");  // invalidate caches before reading fresh h
}

// ---------------- persistent LSTM scan (B collapsed to 1) ----------------
// 256 blocks; block b owns h elements j = b*4 .. b*4+3 (and their 4 gates = 16 w_hh rows).
// thread (r = tid&15, kk = tid>>4): row r, k-chunk kk (64 wide), w slice held in registers.
__global__ __launch_bounds__(256, 1) void lstm_scan(const float* __restrict__ xw,
                                                    const float* __restrict__ w_hh,
                                                    float* h_buf,
                                                    float* __restrict__ hs_c,
                                                    unsigned* bar) {
    const int tid = threadIdx.x;
    const int b = blockIdx.x;
    const int r  = tid & 15;     // local row 0..15
    const int kk = tid >> 4;     // k-chunk 0..15
    const int gq = r >> 2;       // gate quadrant (i,f,g,o)
    const int jl = r & 3;
    const int grow = gq * H_DIM + b * 4 + jl;  // w_hh row

    // register-resident weight slice: w_hh[grow][kk*64 .. +64)
    float4 w[16];
    {
        const float4* wp = (const float4*)(w_hh + (size_t)grow * H_DIM + kk * 64);
#pragma unroll
        for (int m = 0; m < 16; ++m) w[m] = wp[m];
    }

    __shared__ float h_lds[H_DIM];
    __shared__ float red[16][17];
    __shared__ float gate_lds[16];

    unsigned* cnt = bar;
    unsigned* gen = bar + 32;

    float c_reg = 0.f;   // valid on tid<4

    for (int t = 0; t < SEQ; ++t) {
        float part = 0.f;
        if (t > 0) {
            // stage h (agent-coherent loads; written by all blocks last step)
#pragma unroll
            for (int i = 0; i < 4; ++i) {
                h_lds[tid * 4 + i] =
                    __hip_atomic_load(h_buf + tid * 4 + i, __ATOMIC_RELAXED, __HIP_MEMORY_SCOPE_AGENT);
            }
            __syncthreads();
#pragma unroll
            for (int m = 0; m < 16; ++m) {
                float4 h4 = *(const float4*)&h_lds[kk * 64 + m * 4];
                part += w[m].x * h4.x + w[m].y * h4.y + w[m].z * h4.z + w[m].w * h4.w;
            }
        }
        red[kk][r] = part;
        __syncthreads();
        if (tid < 16) {
            float s = 0.f;
#pragma unroll
            for (int q = 0; q < 16; ++q) s += red[q][tid];
            const int gg = tid >> 2;
            const int jj = b * 4 + (tid & 3);
            gate_lds[tid] = xw[t * G4 + gg * H_DIM + jj] + s;
        }
        __syncthreads();
        if (tid < 4) {
            float iv = gate_lds[tid];
            float fv = gate_lds[4 + tid];
            float gv = gate_lds[8 + tid];
            float ov = gate_lds[12 + tid];
            iv = 1.f / (1.f + expf(-iv));
            fv = 1.f / (1.f + expf(-fv));
            gv = tanhf(gv);
            ov = 1.f / (1.f + expf(-ov));
            c_reg = fv * c_reg + iv * gv;
            float hv = ov * tanhf(c_reg);
            const int j = b * 4 + tid;
            hs_c[t * H_DIM + j] = hv;
            __hip_atomic_store(h_buf + j, hv, __ATOMIC_RELAXED, __HIP_MEMORY_SCOPE_AGENT);
        }
        if (t < SEQ - 1) gridBarrier(cnt, gen, NB_SCAN);
    }
}

// ---------------- broadcast h over the 40 identical batch rows ----------------
__global__ __launch_bounds__(256) void bcast_out(const float* __restrict__ hs_c,
                                                 float* __restrict__ out) {
    const int gi = blockIdx.x * 256 + threadIdx.x;   // float4 index; total 655360
    const int t = gi / (BATCH * (H_DIM / 4));        // /10240
    const int rem = gi - t * (BATCH * (H_DIM / 4));
    const int jq = rem & (H_DIM / 4 - 1);            // %256
    const float4 v = ((const float4*)hs_c)[t * (H_DIM / 4) + jq];
    ((float4*)out)[gi] = v;
}

extern "C" void kernel_launch(void* const* d_in, const int* in_sizes, int n_in,
                              void* d_out, int out_size, void* d_ws, size_t ws_size,
                              hipStream_t stream) {
    const float* features = (const float*)d_in[0];
    const float* w_ih     = (const float*)d_in[1];
    const float* w_hh     = (const float*)d_in[2];
    const float* b_ih     = (const float*)d_in[3];
    const float* b_hh     = (const float*)d_in[4];
    float* out = (float*)d_out;
    float* ws  = (float*)d_ws;

    float* fT    = ws + OFF_FT;
    float* xw    = ws + OFF_XW;
    float* h_buf = ws + OFF_H;
    float* hs_c  = ws + OFF_HS;
    float* part  = ws + OFF_PART;
    unsigned* bar = (unsigned*)d_ws;

    // pick K-split count that fits the workspace
    int KS = 16;
    while (KS > 1 && (OFF_PART + (size_t)KS * SEQ * G4) * 4 > ws_size) KS >>= 1;
    const int kspan = IN_DIM / KS;

    zero_bar<<<1, 256, 0, stream>>>(bar);
    transpose_f<<<IN_DIM / 64, 256, 0, stream>>>(features, fT);
    gemm_partial<<<dim3(G4 / 256, SEQ / 16, KS), 256, 0, stream>>>(w_ih, fT, part, kspan);
    reduce_xw<<<(SEQ * G4) / 256, 256, 0, stream>>>(part, b_ih, b_hh, xw, KS);
    lstm_scan<<<NB_SCAN, 256, 0, stream>>>(xw, w_hh, h_buf, hs_c, bar);
    bcast_out<<<(SEQ * BATCH * H_DIM / 4) / 256, 256, 0, stream>>>(hs_c, out);
}

// Round 2
// 725.878 us; speedup vs baseline: 3.2304x; 3.2304x over previous
//
#include <hip/hip_runtime.h>
#include <hip/hip_bf16.h>
#include <math.h>

#define SEQ 64
#define IN_DIM 16384
#define H_DIM 1024
#define G4 4096   // 4*H
#define BATCH 40
#define NB_SCAN 64
#define NT_SCAN 1024

// ---------------- ws layout (floats) ----------------
// [0 .. 256)            barrier (monotone counter at u32[0])
// [256 .. +1048576)     fT   : features transposed [16384][64]
// [.. +262144)          xw   : [64][4096]
// [.. +1024)            h_buf: [1024]
// [.. +65536)           hs_c : [64][1024]
// [.. +KS*262144)       part : [KS][64][4096]
#define OFF_FT   256
#define OFF_XW   (OFF_FT + (size_t)IN_DIM*SEQ)
#define OFF_H    (OFF_XW + (size_t)SEQ*G4)
#define OFF_HS   (OFF_H + H_DIM)
#define OFF_PART (OFF_HS + (size_t)SEQ*H_DIM)

// ---------------- zero the barrier words ----------------
__global__ void zero_bar(unsigned* bar) {
    bar[threadIdx.x] = 0u;
}

// ---------------- transpose features [64][16384] -> fT [16384][64] ----------------
__global__ __launch_bounds__(256) void transpose_f(const float* __restrict__ f,
                                                   float* __restrict__ fT) {
    __shared__ float lds[64][65];
    const int kb = blockIdx.x;          // 256 blocks, 64-wide k tile
    const int tx = threadIdx.x & 63;    // k within tile
    const int ty = threadIdx.x >> 6;    // 0..3
#pragma unroll
    for (int i = 0; i < 16; ++i) {
        int t = ty * 16 + i;
        lds[tx][t] = f[(size_t)t * IN_DIM + kb * 64 + tx];
    }
    __syncthreads();
#pragma unroll
    for (int i = 0; i < 16; ++i) {
        int r = ty * 16 + i;            // k row within tile
        fT[(size_t)(kb * 64 + r) * 64 + tx] = lds[r][tx];
    }
}

// ---------------- GEMM partials: part[ks][t][j] = sum_{k in split} fT[k][t]*w_ih[j][k] ----------------
__global__ __launch_bounds__(256) void gemm_partial(const float* __restrict__ w_ih,
                                                    const float* __restrict__ fT,
                                                    float* __restrict__ part,
                                                    int kspan) {
    const int tid = threadIdx.x;
    const int j  = blockIdx.x * 256 + tid;   // 16 j-blocks
    const int t0 = blockIdx.y * 16;          // 4 t-blocks
    const int k0 = blockIdx.z * kspan;       // KS k-splits

    float acc[16];
#pragma unroll
    for (int i = 0; i < 16; ++i) acc[i] = 0.f;

    const float* wrow = w_ih + (size_t)j * IN_DIM;
    for (int kc = k0; kc < k0 + kspan; kc += 16) {
        const float4* wp = (const float4*)(wrow + kc);
        float warr[16];
        *(float4*)&warr[0]  = wp[0];
        *(float4*)&warr[4]  = wp[1];
        *(float4*)&warr[8]  = wp[2];
        *(float4*)&warr[12] = wp[3];
        const float* fbase = fT + (size_t)kc * 64 + t0;
#pragma unroll
        for (int kk = 0; kk < 16; ++kk) {
            const float wv = warr[kk];
            const float4* fp = (const float4*)(fbase + kk * 64);
            float4 f0 = fp[0], f1 = fp[1], f2 = fp[2], f3 = fp[3];
            acc[0]  += wv * f0.x; acc[1]  += wv * f0.y; acc[2]  += wv * f0.z; acc[3]  += wv * f0.w;
            acc[4]  += wv * f1.x; acc[5]  += wv * f1.y; acc[6]  += wv * f1.z; acc[7]  += wv * f1.w;
            acc[8]  += wv * f2.x; acc[9]  += wv * f2.y; acc[10] += wv * f2.z; acc[11] += wv * f2.w;
            acc[12] += wv * f3.x; acc[13] += wv * f3.y; acc[14] += wv * f3.z; acc[15] += wv * f3.w;
        }
    }
    float* pp = part + ((size_t)blockIdx.z * SEQ + t0) * G4 + j;
#pragma unroll
    for (int i = 0; i < 16; ++i) pp[(size_t)i * G4] = acc[i];
}

// ---------------- reduce partials + bias -> xw ----------------
__global__ __launch_bounds__(256) void reduce_xw(const float* __restrict__ part,
                                                 const float* __restrict__ b_ih,
                                                 const float* __restrict__ b_hh,
                                                 float* __restrict__ xw, int KS) {
    const int idx = blockIdx.x * 256 + threadIdx.x;  // t*4096 + j
    const int j = idx & (G4 - 1);
    float s = b_ih[j] + b_hh[j];
    for (int ks = 0; ks < KS; ++ks) s += part[(size_t)ks * (SEQ * G4) + idx];
    xw[idx] = s;
}

// ---------------- persistent LSTM scan (B collapsed to 1) ----------------
// 64 blocks x 1024 threads. Block b owns h[j], j in [b*16, b*16+16) -> 64 w_hh
// rows (4 gates x 16 j). Thread (r = tid&63 row, q = tid>>6 k-chunk of 64):
// holds w_hh[row][q*64 .. +64) in 64 VGPRs for the whole scan.
// Cross-block h exchange: agent-scope RELAXED atomics only (they bypass the
// non-coherent L1/L2), ordered by explicit s_waitcnt vmcnt(0) before the
// barrier arrival. NO cache-flushing fences (buffer_inv/wbl2 was 29us/step).
__global__ __launch_bounds__(NT_SCAN, 1) void lstm_scan(const float* __restrict__ xw,
                                                        const float* __restrict__ w_hh,
                                                        float* __restrict__ h_buf,
                                                        float* __restrict__ hs_c,
                                                        unsigned* __restrict__ bar) {
    const int tid = threadIdx.x;
    const int b = blockIdx.x;
    const int r  = tid & 63;     // local gate-row 0..63
    const int q  = tid >> 6;     // k-chunk 0..15 (64 floats each)
    const int g  = r >> 4;       // gate (i,f,g,o)
    const int jl = r & 15;
    const size_t grow = (size_t)g * H_DIM + (size_t)b * 16 + jl;  // w_hh row

    // register-resident weight slice: w_hh[grow][q*64 .. +64)
    float4 w[16];
    {
        const float4* wp = (const float4*)(w_hh + grow * H_DIM + q * 64);
#pragma unroll
        for (int m = 0; m < 16; ++m) w[m] = wp[m];
    }
#pragma unroll
    for (int m = 0; m < 16; ++m) {
        asm volatile("" : "+v"(w[m].x), "+v"(w[m].y), "+v"(w[m].z), "+v"(w[m].w));
    }

    __shared__ float h_lds[H_DIM];
    __shared__ float red[64][17];
    __shared__ float gate_lds[64];

    float c_reg = 0.f;   // live on tid<16

    for (int t = 0; t < SEQ; ++t) {
        float part = 0.f;
        if (t > 0) {
            // coherent (agent-scope) load of last step's h, staged via LDS
            h_lds[tid] = __hip_atomic_load(h_buf + tid, __ATOMIC_RELAXED,
                                           __HIP_MEMORY_SCOPE_AGENT);
            __syncthreads();
#pragma unroll
            for (int m = 0; m < 16; ++m) {
                // all 64 lanes of a wave read the same address -> broadcast
                float4 h4 = *(const float4*)&h_lds[q * 64 + m * 4];
                part += w[m].x * h4.x + w[m].y * h4.y + w[m].z * h4.z + w[m].w * h4.w;
            }
        }
        red[r][q] = part;
        __syncthreads();
        if (tid < 64) {
            float s = 0.f;
#pragma unroll
            for (int qq = 0; qq < 16; ++qq) s += red[tid][qq];
            const int gg = tid >> 4;
            const int jj = b * 16 + (tid & 15);
            gate_lds[tid] = xw[(size_t)t * G4 + (size_t)gg * H_DIM + jj] + s;
        }
        __syncthreads();
        if (tid < 16) {
            float iv = gate_lds[tid];
            float fv = gate_lds[16 + tid];
            float gv = gate_lds[32 + tid];
            float ov = gate_lds[48 + tid];
            iv = 1.f / (1.f + expf(-iv));
            fv = 1.f / (1.f + expf(-fv));
            gv = tanhf(gv);
            ov = 1.f / (1.f + expf(-ov));
            c_reg = fv * c_reg + iv * gv;
            float hv = ov * tanhf(c_reg);
            const int j = b * 16 + tid;
            hs_c[(size_t)t * H_DIM + j] = hv;                       // consumed post-kernel
            __hip_atomic_store(h_buf + j, hv, __ATOMIC_RELAXED,
                               __HIP_MEMORY_SCOPE_AGENT);           // coherent publish
        }
        if (t < SEQ - 1) {
            __syncthreads();                       // all waves done; h stores issued (wave 0)
            asm volatile("s_waitcnt vmcnt(0)" ::: "memory");  // h stores ACKed at coherent point
            if (tid == 0) {
                __hip_atomic_fetch_add(bar, 1u, __ATOMIC_RELAXED, __HIP_MEMORY_SCOPE_AGENT);
                const unsigned target = (unsigned)(NB_SCAN * (t + 1));  // monotone, no reset
                while (__hip_atomic_load(bar, __ATOMIC_RELAXED, __HIP_MEMORY_SCOPE_AGENT) < target) {
                    __builtin_amdgcn_s_sleep(1);
                }
                asm volatile("" ::: "memory");     // compiler fence: don't hoist h loads above spin
            }
            __syncthreads();
        }
    }
}

// ---------------- broadcast h over the 40 identical batch rows ----------------
__global__ __launch_bounds__(256) void bcast_out(const float* __restrict__ hs_c,
                                                 float* __restrict__ out) {
    const int gi = blockIdx.x * 256 + threadIdx.x;   // float4 index; total 655360
    const int t = gi / (BATCH * (H_DIM / 4));        // /10240
    const int rem = gi - t * (BATCH * (H_DIM / 4));
    const int jq = rem & (H_DIM / 4 - 1);            // %256
    const float4 v = ((const float4*)hs_c)[t * (H_DIM / 4) + jq];
    ((float4*)out)[gi] = v;
}

extern "C" void kernel_launch(void* const* d_in, const int* in_sizes, int n_in,
                              void* d_out, int out_size, void* d_ws, size_t ws_size,
                              hipStream_t stream) {
    const float* features = (const float*)d_in[0];
    const float* w_ih     = (const float*)d_in[1];
    const float* w_hh     = (const float*)d_in[2];
    const float* b_ih     = (const float*)d_in[3];
    const float* b_hh     = (const float*)d_in[4];
    float* out = (float*)d_out;
    float* ws  = (float*)d_ws;

    float* fT    = ws + OFF_FT;
    float* xw    = ws + OFF_XW;
    float* h_buf = ws + OFF_H;
    float* hs_c  = ws + OFF_HS;
    float* part  = ws + OFF_PART;
    unsigned* bar = (unsigned*)d_ws;

    // pick K-split count that fits the workspace
    int KS = 16;
    while (KS > 1 && (OFF_PART + (size_t)KS * SEQ * G4) * 4 > ws_size) KS >>= 1;
    const int kspan = IN_DIM / KS;

    zero_bar<<<1, 256, 0, stream>>>(bar);
    transpose_f<<<IN_DIM / 64, 256, 0, stream>>>(features, fT);
    gemm_partial<<<dim3(G4 / 256, SEQ / 16, KS), 256, 0, stream>>>(w_ih, fT, part, kspan);
    reduce_xw<<<(SEQ * G4) / 256, 256, 0, stream>>>(part, b_ih, b_hh, xw, KS);
    lstm_scan<<<NB_SCAN, NT_SCAN, 0, stream>>>(xw, w_hh, h_buf, hs_c, bar);
    bcast_out<<<(SEQ * BATCH * H_DIM / 4) / 256, 256, 0, stream>>>(hs_c, out);
}